// Round 1
// baseline (603.371 us; speedup 1.0000x reference)
//
#include <hip/hip_runtime.h>
#include <hip/hip_bf16.h>

// PropNet fused MFMA-bf16 implementation for MI355X (gfx950).
// B=2 N=64 R=16 D=64 H=256 EOUT=64 PSTEP=2
// node rows nr = (b*64+i)*16 + r            (2048)
// edge rows er = ((b*64+i)*64 + j)*16 + r   (131072)
//
// Dataflow:
//   ksmall1: node_enc=relu(nr@neW+neb), X1=nr@eeW[:64], X2=nr@eeW[64:]
//   ksmall2: E1=ne@ep0W1[0:256], E2=ne@ep0W1[256:512], NE1=ne@npW1[0:256]
//   kstep<true> : e0=relu(X1[i]+X2[j]+eeb); h=relu(e0@W1c+E1[i]+E2[j]+b1);
//                 eff=relu(h@W2+b2) -> bf16 ws; agg[i]=sum_j eff
//   ksmall3: g=relu(NE1+ne@npW1[256:512]+agg@npW1[512:768]+npb1);
//            nf=relu(g@npW2+npb2); E1=nf@ep1W1[0:256]; E2=nf@ep1W1[256:512]
//   kstep<false>: same on eff in-place with ep1 weights (no agg; 2nd node
//                 update is dead code since node_effect is unused afterwards)
//   kpred: p=relu(eff@prW1[0:256] + e0@prW1[256:512] + prb1); out=p@prW2+prb2
//
// Big GEMMs use v_mfma_f32_16x16x32_bf16. Weights are pre-packed once per
// launch into fragment order with the SAME (lane,elem)->k map used by the
// LDS A-fragment reads, so any k-permutation mismatch vs HW cancels.

typedef __attribute__((ext_vector_type(8))) short short8;
typedef __attribute__((ext_vector_type(4))) float f32x4;
typedef __attribute__((ext_vector_type(2))) unsigned int u32x2;

#define DI __device__ __forceinline__

// ---------------- workspace layout (bytes) ----------------
constexpr size_t WF_SZ   = (size_t)8 * 16 * 64 * 8 * 2;   // 131072 B per 256x256 bf16 frag matrix
constexpr size_t OFF_WF0 = 0;                  // ep0_W1[512:768] (W1c step0)
constexpr size_t OFF_WF1 = OFF_WF0 + WF_SZ;    // ep0_W2
constexpr size_t OFF_WF2 = OFF_WF1 + WF_SZ;    // ep1_W1[512:768]
constexpr size_t OFF_WF3 = OFF_WF2 + WF_SZ;    // ep1_W2
constexpr size_t OFF_WF4 = OFF_WF3 + WF_SZ;    // pr_W1[0:256]   (applied to eff)
constexpr size_t OFF_WF5 = OFF_WF4 + WF_SZ;    // pr_W1[256:512] (applied to e0)
constexpr size_t OFF_WF6 = OFF_WF5 + WF_SZ;    // pr_W2 256x64 -> 32768 B
constexpr size_t OFF_NENC = OFF_WF6 + 32768;
constexpr size_t SMALLSZ  = (size_t)2048 * 256 * 4;       // 2 MiB
constexpr size_t OFF_X1  = OFF_NENC + SMALLSZ;
constexpr size_t OFF_X2  = OFF_X1 + SMALLSZ;
constexpr size_t OFF_E1  = OFF_X2 + SMALLSZ;
constexpr size_t OFF_E2  = OFF_E1 + SMALLSZ;
constexpr size_t OFF_NE1 = OFF_E2 + SMALLSZ;
constexpr size_t OFF_AGG = OFF_NE1 + SMALLSZ;
constexpr size_t OFF_EFF = OFF_AGG + SMALLSZ;             // bf16 131072x256 = 64 MiB
// total ~82.6 MB

DI unsigned short f2bf(float f) {
    unsigned u = __builtin_bit_cast(unsigned, f);
    u += 0x7fffu + ((u >> 16) & 1u);
    return (unsigned short)(u >> 16);
}

// (lane-group g, element e) -> k offset within a 32-wide K tile.
// Stacked-half layout: e0..3 -> k = 4g+e ; e4..7 -> k = 16+4g+(e-4).
DI int kmap(int g, int e) { return 4 * g + (e & 3) + ((e >> 2) << 4); }

// ---------------- weight repack: f32 [K x ld] -> bf16 fragment order ----------------
// frag (kt,nt): elem index = ((kt*NT + nt)*64 + lane)*8 + e
__global__ __launch_bounds__(64) void kconv(const float* ep0W1, const float* ep0W2,
                                            const float* ep1W1, const float* ep1W2,
                                            const float* prW1, const float* prW2,
                                            unsigned short* wsu)
{
    int bid = blockIdx.x, l = threadIdx.x;
    const float* src; unsigned short* dst; int NT, ld, f;
    if (bid < 768) {
        int m = bid >> 7; f = bid & 127; NT = 16; ld = 256;
        switch (m) {
            case 0:  src = ep0W1 + 512 * 256; dst = wsu + OFF_WF0 / 2; break;
            case 1:  src = ep0W2;             dst = wsu + OFF_WF1 / 2; break;
            case 2:  src = ep1W1 + 512 * 256; dst = wsu + OFF_WF2 / 2; break;
            case 3:  src = ep1W2;             dst = wsu + OFF_WF3 / 2; break;
            case 4:  src = prW1;              dst = wsu + OFF_WF4 / 2; break;
            default: src = prW1 + 256 * 256;  dst = wsu + OFF_WF5 / 2; break;
        }
    } else { f = bid - 768; NT = 4; ld = 64; src = prW2; dst = wsu + OFF_WF6 / 2; }
    int kt = f / NT, nt = f % NT;
    int g = l >> 4, c = nt * 16 + (l & 15);
    unsigned short* o = dst + (size_t)((kt * NT + nt) * 64 + l) * 8;
#pragma unroll
    for (int e = 0; e < 8; ++e) {
        int k = 32 * kt + kmap(g, e);
        o[e] = f2bf(src[(size_t)k * ld + c]);
    }
}

// ---------------- node encoder + edge-encoder partials ----------------
__global__ __launch_bounds__(256) void ksmall1(const float* node_rep, const float* neW,
                                               const float* neb, const float* eeW,
                                               float* node_enc, float* X1, float* X2)
{
    __shared__ float a[64];
    int nr = blockIdx.x, t = threadIdx.x;
    if (t < 64) a[t] = node_rep[(size_t)nr * 64 + t];
    __syncthreads();
    float s0 = 0.f, s1 = 0.f, s2 = 0.f;
#pragma unroll 4
    for (int k = 0; k < 64; ++k) {
        float av = a[k];
        s0 = fmaf(av, neW[(size_t)k * 256 + t], s0);
        s1 = fmaf(av, eeW[(size_t)k * 256 + t], s1);
        s2 = fmaf(av, eeW[(size_t)(64 + k) * 256 + t], s2);
    }
    size_t o = (size_t)nr * 256 + t;
    node_enc[o] = fmaxf(s0 + neb[t], 0.f);
    X1[o] = s1;
    X2[o] = s2;
}

// ---------------- E1_0 / E2_0 / NE1 from node_enc ----------------
__global__ __launch_bounds__(256) void ksmall2(const float* node_enc, const float* ep0W1,
                                               const float* npW1,
                                               float* E1, float* E2, float* NE1)
{
    __shared__ float a[8][256];
    int r0 = blockIdx.x * 8, t = threadIdx.x;
#pragma unroll
    for (int rr = 0; rr < 8; ++rr) a[rr][t] = node_enc[(size_t)(r0 + rr) * 256 + t];
    __syncthreads();
    float A[8] = {0,0,0,0,0,0,0,0}, Bv[8] = {0,0,0,0,0,0,0,0}, C[8] = {0,0,0,0,0,0,0,0};
#pragma unroll 2
    for (int k = 0; k < 256; ++k) {
        float wA = ep0W1[(size_t)k * 256 + t];
        float wB = ep0W1[(size_t)(256 + k) * 256 + t];
        float wC = npW1[(size_t)k * 256 + t];
#pragma unroll
        for (int rr = 0; rr < 8; ++rr) {
            float av = a[rr][k];
            A[rr]  = fmaf(av, wA, A[rr]);
            Bv[rr] = fmaf(av, wB, Bv[rr]);
            C[rr]  = fmaf(av, wC, C[rr]);
        }
    }
#pragma unroll
    for (int rr = 0; rr < 8; ++rr) {
        size_t o = (size_t)(r0 + rr) * 256 + t;
        E1[o] = A[rr]; E2[o] = Bv[rr]; NE1[o] = C[rr];
    }
}

// ---------------- node update (step-1 only) + E1_1/E2_1 ----------------
__global__ __launch_bounds__(256) void ksmall3(const float* node_enc, const float* agg,
                                               const float* NE1, const float* npW1,
                                               const float* npb1, const float* npW2,
                                               const float* npb2, const float* ep1W1,
                                               float* E1, float* E2)
{
    __shared__ float a[8][256];
    __shared__ float c[8][256];
    int r0 = blockIdx.x * 8, t = threadIdx.x;
#pragma unroll
    for (int rr = 0; rr < 8; ++rr) {
        a[rr][t] = node_enc[(size_t)(r0 + rr) * 256 + t];
        c[rr][t] = agg[(size_t)(r0 + rr) * 256 + t];
    }
    __syncthreads();
    float acc[8] = {0,0,0,0,0,0,0,0};
#pragma unroll 2
    for (int k = 0; k < 256; ++k) {
        float w1 = npW1[(size_t)(256 + k) * 256 + t];
        float w2 = npW1[(size_t)(512 + k) * 256 + t];
#pragma unroll
        for (int rr = 0; rr < 8; ++rr)
            acc[rr] += a[rr][k] * w1 + c[rr][k] * w2;
    }
    __syncthreads();
#pragma unroll
    for (int rr = 0; rr < 8; ++rr)
        c[rr][t] = fmaxf(acc[rr] + NE1[(size_t)(r0 + rr) * 256 + t] + npb1[t], 0.f);
    __syncthreads();
    float acc2[8] = {0,0,0,0,0,0,0,0};
#pragma unroll 2
    for (int k = 0; k < 256; ++k) {
        float w = npW2[(size_t)k * 256 + t];
#pragma unroll
        for (int rr = 0; rr < 8; ++rr) acc2[rr] += c[rr][k] * w;
    }
    __syncthreads();
#pragma unroll
    for (int rr = 0; rr < 8; ++rr) a[rr][t] = fmaxf(acc2[rr] + npb2[t], 0.f);
    __syncthreads();
    float eA[8] = {0,0,0,0,0,0,0,0}, eB[8] = {0,0,0,0,0,0,0,0};
#pragma unroll 2
    for (int k = 0; k < 256; ++k) {
        float w1 = ep1W1[(size_t)k * 256 + t];
        float w2 = ep1W1[(size_t)(256 + k) * 256 + t];
#pragma unroll
        for (int rr = 0; rr < 8; ++rr) {
            eA[rr] += a[rr][k] * w1;
            eB[rr] += a[rr][k] * w2;
        }
    }
#pragma unroll
    for (int rr = 0; rr < 8; ++rr) {
        size_t o = (size_t)(r0 + rr) * 256 + t;
        E1[o] = eA[rr]; E2[o] = eB[rr];
    }
}

// ---------------- MFMA tile helpers ----------------
// LDS tile: 64 rows x 256 bf16, row stride 512 B, XOR swizzle byte ^= (row&7)<<4
DI short8 load_afrag(const unsigned char* lds, int row, int kt, int g) {
    int sw = (row & 7) << 4;
    int kb = 64 * kt + 8 * g;            // byte offset of elems 0..3 (k = 32kt+4g)
    union { short8 s; u32x2 u[2]; } u_;
    u_.u[0] = *(const u32x2*)(lds + row * 512 + (kb ^ sw));
    u_.u[1] = *(const u32x2*)(lds + row * 512 + ((kb + 32) ^ sw));   // k+16 half
    return u_.s;
}

// acc[mi][ni] += Atile(64x256, LDS) @ W(256 x 256, frag order); wave wv owns cols 64*wv..+63
DI void gemm_tile(const unsigned char* lds, const unsigned short* Wf,
                  f32x4 (&acc)[4][4], int wv, int l) {
    const int g = l >> 4, l15 = l & 15;
    for (int kt = 0; kt < 8; ++kt) {
        short8 af[4];
#pragma unroll
        for (int mi = 0; mi < 4; ++mi) af[mi] = load_afrag(lds, 16 * mi + l15, kt, g);
        short8 bf[4];
#pragma unroll
        for (int ni = 0; ni < 4; ++ni)
            bf[ni] = *(const short8*)(Wf + (size_t)((kt * 16 + 4 * wv + ni) * 64 + l) * 8);
#pragma unroll
        for (int ni = 0; ni < 4; ++ni)
#pragma unroll
            for (int mi = 0; mi < 4; ++mi)
                acc[mi][ni] = __builtin_amdgcn_mfma_f32_16x16x32_bf16(af[mi], bf[ni], acc[mi][ni], 0, 0, 0);
    }
}

// ---------------- fused edge propagation step ----------------
template <bool FIRST>
__global__ __launch_bounds__(256) void kstep(const float* X1, const float* X2, const float* eeb,
                                             const float* E1, const float* E2,
                                             const float* b1, const float* b2,
                                             const unsigned short* WfA, const unsigned short* WfB,
                                             unsigned short* eff, float* agg)
{
    __shared__ __align__(16) unsigned char lds[64 * 512];
    const int bir = blockIdx.x, tid = threadIdx.x;
    const int b = bir >> 10, r = bir & 15;
    const int ebase = (bir >> 4) * 1024 + r;          // er = ebase + j*16

    // phase 0: build A tile (rows = senders j)
    {
        int rlo = tid >> 5;
        int c0 = (tid & 31) * 8;
        for (int p = 0; p < 8; ++p) {
            int row = p * 8 + rlo;
            union { short8 s; unsigned short u[8]; } v;
            if (FIRST) {
                int nrj = b * 1024 + row * 16 + r;
#pragma unroll
                for (int e = 0; e < 8; ++e) {
                    float x = X1[(size_t)bir * 256 + c0 + e] + X2[(size_t)nrj * 256 + c0 + e] + eeb[c0 + e];
                    v.u[e] = f2bf(fmaxf(x, 0.f));
                }
            } else {
                v.s = *(const short8*)(eff + (size_t)(ebase + row * 16) * 256 + c0);
            }
            *(short8*)&lds[row * 512 + ((c0 * 2) ^ ((row & 7) << 4))] = v.s;
        }
    }
    __syncthreads();

    const int l = tid & 63, wv = tid >> 6, g = l >> 4, l15 = l & 15;
    f32x4 acc[4][4];
#pragma unroll
    for (int mi = 0; mi < 4; ++mi)
#pragma unroll
        for (int ni = 0; ni < 4; ++ni) acc[mi][ni] = (f32x4){0.f, 0.f, 0.f, 0.f};

    gemm_tile(lds, WfA, acc, wv, l);

    // epilogue 1: h = relu(acc + E1[receiver] + E2[sender j] + b1) -> LDS bf16
    __syncthreads();
#pragma unroll
    for (int ni = 0; ni < 4; ++ni) {
        int col = 64 * wv + 16 * ni + l15;
        float e1b = E1[(size_t)bir * 256 + col] + b1[col];
#pragma unroll
        for (int mi = 0; mi < 4; ++mi) {
#pragma unroll
            for (int q = 0; q < 4; ++q) {
                int row = 16 * mi + 4 * g + q;
                float e2 = E2[(size_t)(b * 1024 + row * 16 + r) * 256 + col];
                float h = fmaxf(acc[mi][ni][q] + e1b + e2, 0.f);
                *(unsigned short*)&lds[row * 512 + ((col * 2) ^ ((row & 7) << 4))] = f2bf(h);
                acc[mi][ni][q] = 0.f;
            }
        }
    }
    __syncthreads();

    gemm_tile(lds, WfB, acc, wv, l);

    // epilogue 2: eff = relu(acc + b2), store bf16; block-local agg (step 1 only)
#pragma unroll
    for (int ni = 0; ni < 4; ++ni) {
        int col = 64 * wv + 16 * ni + l15;
        float bb = b2[col];
        float s = 0.f;
#pragma unroll
        for (int mi = 0; mi < 4; ++mi) {
#pragma unroll
            for (int q = 0; q < 4; ++q) {
                int row = 16 * mi + 4 * g + q;
                float e = fmaxf(acc[mi][ni][q] + bb, 0.f);
                eff[(size_t)(ebase + row * 16) * 256 + col] = f2bf(e);
                if (FIRST) s += e;
            }
        }
        if (FIRST) {
            s += __shfl_xor(s, 16);
            s += __shfl_xor(s, 32);
            if (l < 16) agg[(size_t)bir * 256 + 64 * wv + 16 * ni + l] = s;
        }
    }
}

// ---------------- fused edge predictor ----------------
__global__ __launch_bounds__(256) void kpred(const float* X1, const float* X2, const float* eeb,
                                             const unsigned short* eff,
                                             const unsigned short* WfA, const unsigned short* WfB,
                                             const unsigned short* Wf2,
                                             const float* prb1, const float* prb2, float* out)
{
    __shared__ __align__(16) unsigned char ldsA[64 * 512];
    __shared__ __align__(16) unsigned char ldsB[64 * 512];
    const int bir = blockIdx.x, tid = threadIdx.x;
    const int b = bir >> 10, r = bir & 15;
    const int ebase = (bir >> 4) * 1024 + r;

    // phase 0: ldsA = eff rows, ldsB = recomputed edge_enc rows
    {
        int rlo = tid >> 5;
        int c0 = (tid & 31) * 8;
        for (int p = 0; p < 8; ++p) {
            int row = p * 8 + rlo;
            int swz = (c0 * 2) ^ ((row & 7) << 4);
            short8 sv = *(const short8*)(eff + (size_t)(ebase + row * 16) * 256 + c0);
            *(short8*)&ldsA[row * 512 + swz] = sv;
            union { short8 s; unsigned short u[8]; } v;
            int nrj = b * 1024 + row * 16 + r;
#pragma unroll
            for (int e = 0; e < 8; ++e) {
                float x = X1[(size_t)bir * 256 + c0 + e] + X2[(size_t)nrj * 256 + c0 + e] + eeb[c0 + e];
                v.u[e] = f2bf(fmaxf(x, 0.f));
            }
            *(short8*)&ldsB[row * 512 + swz] = v.s;
        }
    }
    __syncthreads();

    const int l = tid & 63, wv = tid >> 6, g = l >> 4, l15 = l & 15;
    f32x4 acc[4][4];
#pragma unroll
    for (int mi = 0; mi < 4; ++mi)
#pragma unroll
        for (int ni = 0; ni < 4; ++ni) acc[mi][ni] = (f32x4){0.f, 0.f, 0.f, 0.f};

    gemm_tile(ldsA, WfA, acc, wv, l);   // eff @ pr_W1[0:256]
    gemm_tile(ldsB, WfB, acc, wv, l);   // e0  @ pr_W1[256:512]

    // p = relu(acc + prb1) -> ldsA (bf16)
    __syncthreads();
#pragma unroll
    for (int ni = 0; ni < 4; ++ni) {
        int col = 64 * wv + 16 * ni + l15;
        float pb = prb1[col];
#pragma unroll
        for (int mi = 0; mi < 4; ++mi) {
#pragma unroll
            for (int q = 0; q < 4; ++q) {
                int row = 16 * mi + 4 * g + q;
                float p = fmaxf(acc[mi][ni][q] + pb, 0.f);
                *(unsigned short*)&ldsA[row * 512 + ((col * 2) ^ ((row & 7) << 4))] = f2bf(p);
            }
        }
    }
    __syncthreads();

    // out = p @ pr_W2 + prb2 : 64 output cols, wave wv owns cols 16*wv..+15
    f32x4 acc3[4];
#pragma unroll
    for (int mi = 0; mi < 4; ++mi) acc3[mi] = (f32x4){0.f, 0.f, 0.f, 0.f};
    for (int kt = 0; kt < 8; ++kt) {
        short8 bf = *(const short8*)(Wf2 + (size_t)((kt * 4 + wv) * 64 + l) * 8);
#pragma unroll
        for (int mi = 0; mi < 4; ++mi) {
            short8 af = load_afrag(ldsA, 16 * mi + l15, kt, g);
            acc3[mi] = __builtin_amdgcn_mfma_f32_16x16x32_bf16(af, bf, acc3[mi], 0, 0, 0);
        }
    }
    int colo = 16 * wv + l15;
    float pb2 = prb2[colo];
#pragma unroll
    for (int mi = 0; mi < 4; ++mi) {
#pragma unroll
        for (int q = 0; q < 4; ++q) {
            int row = 16 * mi + 4 * g + q;
            out[(size_t)(ebase + row * 16) * 64 + colo] = acc3[mi][q] + pb2;
        }
    }
}

// ---------------- host ----------------
extern "C" void kernel_launch(void* const* d_in, const int* in_sizes, int n_in,
                              void* d_out, int out_size, void* d_ws, size_t ws_size,
                              hipStream_t stream)
{
    (void)in_sizes; (void)n_in; (void)out_size; (void)ws_size;
    const float* node_rep = (const float*)d_in[0];
    const float* neW   = (const float*)d_in[1];
    const float* neb   = (const float*)d_in[2];
    const float* eeW   = (const float*)d_in[3];
    const float* eeb   = (const float*)d_in[4];
    const float* npW1  = (const float*)d_in[5];
    const float* npb1  = (const float*)d_in[6];
    const float* npW2  = (const float*)d_in[7];
    const float* npb2  = (const float*)d_in[8];
    const float* ep0W1 = (const float*)d_in[9];
    const float* ep0b1 = (const float*)d_in[10];
    const float* ep0W2 = (const float*)d_in[11];
    const float* ep0b2 = (const float*)d_in[12];
    const float* ep1W1 = (const float*)d_in[13];
    const float* ep1b1 = (const float*)d_in[14];
    const float* ep1W2 = (const float*)d_in[15];
    const float* ep1b2 = (const float*)d_in[16];
    const float* prW1  = (const float*)d_in[17];
    const float* prb1  = (const float*)d_in[18];
    const float* prW2  = (const float*)d_in[19];
    const float* prb2  = (const float*)d_in[20];

    char* ws = (char*)d_ws;
    unsigned short* wsu = (unsigned short*)ws;
    float* node_enc = (float*)(ws + OFF_NENC);
    float* X1  = (float*)(ws + OFF_X1);
    float* X2  = (float*)(ws + OFF_X2);
    float* E1  = (float*)(ws + OFF_E1);
    float* E2  = (float*)(ws + OFF_E2);
    float* NE1 = (float*)(ws + OFF_NE1);
    float* agg = (float*)(ws + OFF_AGG);
    unsigned short* eff = (unsigned short*)(ws + OFF_EFF);
    const unsigned short* wf0 = (const unsigned short*)(ws + OFF_WF0);
    const unsigned short* wf1 = (const unsigned short*)(ws + OFF_WF1);
    const unsigned short* wf2 = (const unsigned short*)(ws + OFF_WF2);
    const unsigned short* wf3 = (const unsigned short*)(ws + OFF_WF3);
    const unsigned short* wf4 = (const unsigned short*)(ws + OFF_WF4);
    const unsigned short* wf5 = (const unsigned short*)(ws + OFF_WF5);
    const unsigned short* wf6 = (const unsigned short*)(ws + OFF_WF6);

    kconv<<<dim3(800), dim3(64), 0, stream>>>(ep0W1, ep0W2, ep1W1, ep1W2, prW1, prW2, wsu);
    ksmall1<<<dim3(2048), dim3(256), 0, stream>>>(node_rep, neW, neb, eeW, node_enc, X1, X2);
    ksmall2<<<dim3(256), dim3(256), 0, stream>>>(node_enc, ep0W1, npW1, E1, E2, NE1);
    kstep<true><<<dim3(2048), dim3(256), 0, stream>>>(X1, X2, eeb, E1, E2, ep0b1, ep0b2,
                                                      wf0, wf1, eff, agg);
    ksmall3<<<dim3(256), dim3(256), 0, stream>>>(node_enc, agg, NE1, npW1, npb1, npW2, npb2,
                                                 ep1W1, E1, E2);
    kstep<false><<<dim3(2048), dim3(256), 0, stream>>>(X1, X2, eeb, E1, E2, ep1b1, ep1b2,
                                                       wf2, wf3, eff, nullptr);
    kpred<<<dim3(2048), dim3(256), 0, stream>>>(X1, X2, eeb, eff, wf4, wf5, wf6,
                                                prb1, prb2, (float*)d_out);
}

// Round 2
// 464.379 us; speedup vs baseline: 1.2993x; 1.2993x over previous
//
#include <hip/hip_runtime.h>
#include <hip/hip_bf16.h>

// PropNet fused MFMA-bf16 implementation for MI355X (gfx950).
// B=2 N=64 R=16 D=64 H=256 EOUT=64 PSTEP=2
// node rows nr = (b*64+i)*16 + r            (2048)
// edge rows er = ((b*64+i)*64 + j)*16 + r   (131072)
//
// R1 changes vs R0:
//  - node path (ksmall1/2/3, was ~270+ us latency-bound VALU GEMVs at 11% occ)
//    rewritten as MFMA kernels knode12/knode3 (32 blocks x 64-row tiles).
//  - kstep<false> + kpred fused into kstep2pred (same block<->tile mapping;
//    kills 64MB eff write + 64MB read + one staging phase + one launch).
//
// All GEMMs: v_mfma_f32_16x16x32_bf16. Weights pre-packed into fragment order
// with the SAME (lane,elem)->k map as the LDS A-fragment reads, so any k-map
// mismatch vs HW cancels. LDS tiles XOR-swizzled: byte ^= (row&7)<<4.

typedef __attribute__((ext_vector_type(8))) short short8;
typedef __attribute__((ext_vector_type(4))) float f32x4;
typedef __attribute__((ext_vector_type(2))) unsigned int u32x2;

#define DI __device__ __forceinline__

// ---------------- workspace layout (bytes) ----------------
constexpr size_t WF_SZ = 131072;            // 256x256 bf16 frag matrix
// full 256x256 frag matrices, index:
// 0 ep0W1c(=ep0W1[512:768]) 1 ep0W2 2 ep1W1c 3 ep1W2 4 prW1a(=prW1[0:256])
// 5 prW1b(=prW1[256:512]) 6 E1w(=ep0W1[0:256]) 7 E2w(=ep0W1[256:512])
// 8 NE2w(=npW1[256:512]) 9 NAGGw(=npW1[512:768]) 10 NE1w(=npW1[0:256])
// 11 npW2 12 ep1Aw(=ep1W1[0:256]) 13 ep1Bw(=ep1W1[256:512])
constexpr size_t OFF_NEW  = 14 * WF_SZ;     // neW   64x256 frag (32 KB)
constexpr size_t OFF_EE1  = OFF_NEW + 32768; // eeW[0:64]
constexpr size_t OFF_EE2  = OFF_EE1 + 32768; // eeW[64:128]
constexpr size_t OFF_PW2  = OFF_EE2 + 32768; // prW2 256x64 frag
constexpr size_t OFF_NENC = OFF_PW2 + 32768; // node_enc bf16 [2048,256] 1MB
constexpr size_t OFF_X1   = OFF_NENC + (size_t)2048 * 256 * 2;
constexpr size_t SM = (size_t)2048 * 256 * 4;
constexpr size_t OFF_X2  = OFF_X1 + SM;
constexpr size_t OFF_E1  = OFF_X2 + SM;
constexpr size_t OFF_E2  = OFF_E1 + SM;
constexpr size_t OFF_NE1 = OFF_E2 + SM;
constexpr size_t OFF_AGG = OFF_NE1 + SM;
constexpr size_t OFF_EFF = OFF_AGG + SM;     // bf16 131072x256 = 64 MiB
// total ~79 MB

DI unsigned short f2bf(float f) {
    unsigned u = __builtin_bit_cast(unsigned, f);
    u += 0x7fffu + ((u >> 16) & 1u);
    return (unsigned short)(u >> 16);
}

// (lane-group g, element e) -> k offset within a 32-wide K tile.
DI int kmap(int g, int e) { return 4 * g + (e & 3) + ((e >> 2) << 4); }

// ---------------- weight repack: f32 [K x ld] -> bf16 fragment order ----------------
__global__ __launch_bounds__(64) void kconv(const float* ep0W1, const float* ep0W2,
                                            const float* ep1W1, const float* ep1W2,
                                            const float* prW1, const float* prW2,
                                            const float* npW1, const float* npW2,
                                            const float* neW, const float* eeW,
                                            unsigned short* wsu)
{
    int bid = blockIdx.x, l = threadIdx.x;
    const float* src; unsigned short* dst; int NT = 16, ld = 256, f;
    if (bid < 1792) {
        int m = bid >> 7; f = bid & 127;
        switch (m) {
            case 0:  src = ep0W1 + 512 * 256; break;
            case 1:  src = ep0W2;             break;
            case 2:  src = ep1W1 + 512 * 256; break;
            case 3:  src = ep1W2;             break;
            case 4:  src = prW1;              break;
            case 5:  src = prW1 + 256 * 256;  break;
            case 6:  src = ep0W1;             break;
            case 7:  src = ep0W1 + 256 * 256; break;
            case 8:  src = npW1 + 256 * 256;  break;
            case 9:  src = npW1 + 512 * 256;  break;
            case 10: src = npW1;              break;
            case 11: src = npW2;              break;
            case 12: src = ep1W1;             break;
            default: src = ep1W1 + 256 * 256; break;
        }
        dst = wsu + (size_t)m * (WF_SZ / 2);
    } else if (bid < 1888) {
        int m = (bid - 1792) >> 5; f = (bid - 1792) & 31;
        src = (m == 0) ? neW : (m == 1) ? eeW : eeW + 64 * 256;
        dst = wsu + ((m == 0) ? OFF_NEW : (m == 1) ? OFF_EE1 : OFF_EE2) / 2;
    } else {
        f = bid - 1888; NT = 4; ld = 64; src = prW2; dst = wsu + OFF_PW2 / 2;
    }
    int kt = f / NT, nt = f % NT;
    int g = l >> 4, c = nt * 16 + (l & 15);
    unsigned short* o = dst + (size_t)((kt * NT + nt) * 64 + l) * 8;
#pragma unroll
    for (int e = 0; e < 8; ++e) {
        int k = 32 * kt + kmap(g, e);
        o[e] = f2bf(src[(size_t)k * ld + c]);
    }
}

// ---------------- MFMA tile helpers ----------------
// LDS tile: rows x (LDB bytes), XOR swizzle byte ^= (row&7)<<4
template <int LDB>
DI short8 load_afrag(const unsigned char* lds, int row, int kt, int g) {
    int sw = (row & 7) << 4;
    int kb = 64 * kt + 8 * g;
    union { short8 s; u32x2 u[2]; } u_;
    u_.u[0] = *(const u32x2*)(lds + row * LDB + (kb ^ sw));
    u_.u[1] = *(const u32x2*)(lds + row * LDB + ((kb + 32) ^ sw));
    return u_.s;
}

DI void zero_acc(f32x4 (&acc)[4][4]) {
#pragma unroll
    for (int mi = 0; mi < 4; ++mi)
#pragma unroll
        for (int ni = 0; ni < 4; ++ni) acc[mi][ni] = (f32x4){0.f, 0.f, 0.f, 0.f};
}

// acc += Atile(64 x 32*KT, LDS) @ W(32*KT x 256, frag order); wave wv owns cols 64*wv..+63
template <int KT, int LDB>
DI void gemm_tile(const unsigned char* lds, const unsigned short* Wf,
                  f32x4 (&acc)[4][4], int wv, int l) {
    const int g = l >> 4, l15 = l & 15;
    for (int kt = 0; kt < KT; ++kt) {
        short8 af[4];
#pragma unroll
        for (int mi = 0; mi < 4; ++mi) af[mi] = load_afrag<LDB>(lds, 16 * mi + l15, kt, g);
        short8 bf[4];
#pragma unroll
        for (int ni = 0; ni < 4; ++ni)
            bf[ni] = *(const short8*)(Wf + (size_t)((kt * 16 + 4 * wv + ni) * 64 + l) * 8);
#pragma unroll
        for (int ni = 0; ni < 4; ++ni)
#pragma unroll
            for (int mi = 0; mi < 4; ++mi)
                acc[mi][ni] = __builtin_amdgcn_mfma_f32_16x16x32_bf16(af[mi], bf[ni], acc[mi][ni], 0, 0, 0);
    }
}

DI void store_tile_f32(float* dst, int r0, f32x4 (&acc)[4][4], int wv, int l) {
    int g = l >> 4, l15 = l & 15;
#pragma unroll
    for (int ni = 0; ni < 4; ++ni) {
        int col = 64 * wv + 16 * ni + l15;
#pragma unroll
        for (int mi = 0; mi < 4; ++mi)
#pragma unroll
            for (int q = 0; q < 4; ++q)
                dst[(size_t)(r0 + 16 * mi + 4 * g + q) * 256 + col] = acc[mi][ni][q];
    }
}

// ---------------- node path: encoder + edge-enc partials + E1/E2/NE1 ----------------
__global__ __launch_bounds__(256) void knode12(const float* node_rep, const float* neb,
        const unsigned short* neWf, const unsigned short* eeW1f, const unsigned short* eeW2f,
        const unsigned short* E1wf, const unsigned short* E2wf, const unsigned short* NE1wf,
        unsigned short* node_enc, float* X1, float* X2, float* E1, float* E2, float* NE1)
{
    __shared__ __align__(16) unsigned char ldsA[64 * 128];
    __shared__ __align__(16) unsigned char ldsB[64 * 512];
    const int r0 = blockIdx.x * 64, tid = threadIdx.x;
    {
        int row = tid >> 2, c0 = (tid & 3) * 16;
        const float* src = node_rep + (size_t)(r0 + row) * 64 + c0;
        union { short8 s; unsigned short u[8]; } v0, v1;
#pragma unroll
        for (int e = 0; e < 8; ++e) { v0.u[e] = f2bf(src[e]); v1.u[e] = f2bf(src[8 + e]); }
        int sw = (row & 7) << 4;
        *(short8*)&ldsA[row * 128 + ((c0 * 2) ^ sw)] = v0.s;
        *(short8*)&ldsA[row * 128 + ((c0 * 2 + 16) ^ sw)] = v1.s;
    }
    __syncthreads();
    const int l = tid & 63, wv = tid >> 6, g = l >> 4, l15 = l & 15;
    f32x4 acc[4][4];
    // node_enc = relu(node_rep @ neW + neb) -> bf16 ldsB + global
    zero_acc(acc);
    gemm_tile<2, 128>(ldsA, neWf, acc, wv, l);
#pragma unroll
    for (int ni = 0; ni < 4; ++ni) {
        int col = 64 * wv + 16 * ni + l15;
        float bb = neb[col];
#pragma unroll
        for (int mi = 0; mi < 4; ++mi)
#pragma unroll
            for (int q = 0; q < 4; ++q) {
                int row = 16 * mi + 4 * g + q;
                unsigned short bv = f2bf(fmaxf(acc[mi][ni][q] + bb, 0.f));
                *(unsigned short*)&ldsB[row * 512 + ((col * 2) ^ ((row & 7) << 4))] = bv;
                node_enc[(size_t)(r0 + row) * 256 + col] = bv;
            }
    }
    // X1 = node_rep @ eeW[:64], X2 = node_rep @ eeW[64:]
    zero_acc(acc);
    gemm_tile<2, 128>(ldsA, eeW1f, acc, wv, l);
    store_tile_f32(X1, r0, acc, wv, l);
    zero_acc(acc);
    gemm_tile<2, 128>(ldsA, eeW2f, acc, wv, l);
    store_tile_f32(X2, r0, acc, wv, l);
    __syncthreads();   // all ldsB writes done before K=256 gemms read it
    zero_acc(acc);
    gemm_tile<8, 512>(ldsB, E1wf, acc, wv, l);
    store_tile_f32(E1, r0, acc, wv, l);
    zero_acc(acc);
    gemm_tile<8, 512>(ldsB, E2wf, acc, wv, l);
    store_tile_f32(E2, r0, acc, wv, l);
    zero_acc(acc);
    gemm_tile<8, 512>(ldsB, NE1wf, acc, wv, l);
    store_tile_f32(NE1, r0, acc, wv, l);
}

// ---------------- node update chain (step-1) + E1_1/E2_1 ----------------
__global__ __launch_bounds__(256) void knode3(const unsigned short* node_enc, const float* agg,
        const float* NE1, const float* npb1, const float* npb2,
        const unsigned short* NE2wf, const unsigned short* NAGGwf, const unsigned short* npW2f,
        const unsigned short* ep1Awf, const unsigned short* ep1Bwf,
        float* E1, float* E2)
{
    __shared__ __align__(16) unsigned char ldsA[64 * 512];
    __shared__ __align__(16) unsigned char ldsB[64 * 512];
    const int r0 = blockIdx.x * 64, tid = threadIdx.x;
    {
        int row = tid >> 2, cbase = (tid & 3) * 64;
        int sw = (row & 7) << 4;
#pragma unroll
        for (int cc = 0; cc < 4; ++cc) {
            int c0 = cbase + cc * 16;
            short8 lo = *(const short8*)(node_enc + (size_t)(r0 + row) * 256 + c0);
            short8 hi = *(const short8*)(node_enc + (size_t)(r0 + row) * 256 + c0 + 8);
            *(short8*)&ldsA[row * 512 + ((c0 * 2) ^ sw)] = lo;
            *(short8*)&ldsA[row * 512 + ((c0 * 2 + 16) ^ sw)] = hi;
            union { short8 s; unsigned short u[8]; } v0, v1;
            const float* asrc = agg + (size_t)(r0 + row) * 256 + c0;
#pragma unroll
            for (int e = 0; e < 8; ++e) { v0.u[e] = f2bf(asrc[e]); v1.u[e] = f2bf(asrc[8 + e]); }
            *(short8*)&ldsB[row * 512 + ((c0 * 2) ^ sw)] = v0.s;
            *(short8*)&ldsB[row * 512 + ((c0 * 2 + 16) ^ sw)] = v1.s;
        }
    }
    __syncthreads();
    const int l = tid & 63, wv = tid >> 6, g = l >> 4, l15 = l & 15;
    f32x4 acc[4][4];
    // g = relu(NE1 + node_enc@NE2w + agg@NAGGw + npb1) -> bf16 ldsA
    zero_acc(acc);
    gemm_tile<8, 512>(ldsA, NE2wf, acc, wv, l);
    gemm_tile<8, 512>(ldsB, NAGGwf, acc, wv, l);
    __syncthreads();
#pragma unroll
    for (int ni = 0; ni < 4; ++ni) {
        int col = 64 * wv + 16 * ni + l15;
        float bb = npb1[col];
#pragma unroll
        for (int mi = 0; mi < 4; ++mi)
#pragma unroll
            for (int q = 0; q < 4; ++q) {
                int row = 16 * mi + 4 * g + q;
                float v = fmaxf(acc[mi][ni][q] + NE1[(size_t)(r0 + row) * 256 + col] + bb, 0.f);
                *(unsigned short*)&ldsA[row * 512 + ((col * 2) ^ ((row & 7) << 4))] = f2bf(v);
            }
    }
    __syncthreads();
    // nf = relu(g @ npW2 + npb2) -> bf16 ldsB
    zero_acc(acc);
    gemm_tile<8, 512>(ldsA, npW2f, acc, wv, l);
    __syncthreads();
#pragma unroll
    for (int ni = 0; ni < 4; ++ni) {
        int col = 64 * wv + 16 * ni + l15;
        float bb = npb2[col];
#pragma unroll
        for (int mi = 0; mi < 4; ++mi)
#pragma unroll
            for (int q = 0; q < 4; ++q) {
                int row = 16 * mi + 4 * g + q;
                *(unsigned short*)&ldsB[row * 512 + ((col * 2) ^ ((row & 7) << 4))] =
                    f2bf(fmaxf(acc[mi][ni][q] + bb, 0.f));
            }
    }
    __syncthreads();
    // E1 = nf @ ep1W1[0:256], E2 = nf @ ep1W1[256:512]
    zero_acc(acc);
    gemm_tile<8, 512>(ldsB, ep1Awf, acc, wv, l);
    store_tile_f32(E1, r0, acc, wv, l);
    zero_acc(acc);
    gemm_tile<8, 512>(ldsB, ep1Bwf, acc, wv, l);
    store_tile_f32(E2, r0, acc, wv, l);
}

// ---------------- fused edge propagation step 0 (writes eff + agg) ----------------
__global__ __launch_bounds__(256) void kstep1(const float* X1, const float* X2, const float* eeb,
                                              const float* E1, const float* E2,
                                              const float* b1, const float* b2,
                                              const unsigned short* WfA, const unsigned short* WfB,
                                              unsigned short* eff, float* agg)
{
    __shared__ __align__(16) unsigned char lds[64 * 512];
    const int bir = blockIdx.x, tid = threadIdx.x;
    const int b = bir >> 10, r = bir & 15;
    const int ebase = (bir >> 4) * 1024 + r;          // er = ebase + j*16

    {   // phase 0: build e0 tile (rows = senders j)
        int rlo = tid >> 5;
        int c0 = (tid & 31) * 8;
        for (int p = 0; p < 8; ++p) {
            int row = p * 8 + rlo;
            union { short8 s; unsigned short u[8]; } v;
            int nrj = b * 1024 + row * 16 + r;
#pragma unroll
            for (int e = 0; e < 8; ++e) {
                float x = X1[(size_t)bir * 256 + c0 + e] + X2[(size_t)nrj * 256 + c0 + e] + eeb[c0 + e];
                v.u[e] = f2bf(fmaxf(x, 0.f));
            }
            *(short8*)&lds[row * 512 + ((c0 * 2) ^ ((row & 7) << 4))] = v.s;
        }
    }
    __syncthreads();

    const int l = tid & 63, wv = tid >> 6, g = l >> 4, l15 = l & 15;
    f32x4 acc[4][4];
    zero_acc(acc);
    gemm_tile<8, 512>(lds, WfA, acc, wv, l);
    __syncthreads();
#pragma unroll
    for (int ni = 0; ni < 4; ++ni) {
        int col = 64 * wv + 16 * ni + l15;
        float e1b = E1[(size_t)bir * 256 + col] + b1[col];
#pragma unroll
        for (int mi = 0; mi < 4; ++mi)
#pragma unroll
            for (int q = 0; q < 4; ++q) {
                int row = 16 * mi + 4 * g + q;
                float e2 = E2[(size_t)(b * 1024 + row * 16 + r) * 256 + col];
                float h = fmaxf(acc[mi][ni][q] + e1b + e2, 0.f);
                *(unsigned short*)&lds[row * 512 + ((col * 2) ^ ((row & 7) << 4))] = f2bf(h);
                acc[mi][ni][q] = 0.f;
            }
    }
    __syncthreads();
    gemm_tile<8, 512>(lds, WfB, acc, wv, l);
#pragma unroll
    for (int ni = 0; ni < 4; ++ni) {
        int col = 64 * wv + 16 * ni + l15;
        float bb = b2[col];
        float s = 0.f;
#pragma unroll
        for (int mi = 0; mi < 4; ++mi)
#pragma unroll
            for (int q = 0; q < 4; ++q) {
                int row = 16 * mi + 4 * g + q;
                float e = fmaxf(acc[mi][ni][q] + bb, 0.f);
                eff[(size_t)(ebase + row * 16) * 256 + col] = f2bf(e);
                s += e;
            }
        s += __shfl_xor(s, 16);
        s += __shfl_xor(s, 32);
        if (l < 16) agg[(size_t)bir * 256 + 64 * wv + 16 * ni + l] = s;
    }
}

// ---------------- fused edge step 1 + predictor ----------------
__global__ __launch_bounds__(256) void kstep2pred(const float* X1, const float* X2, const float* eeb,
        const float* E1, const float* E2, const float* b1, const float* b2,
        const unsigned short* WfA, const unsigned short* WfB,
        const unsigned short* WfPA, const unsigned short* WfPB, const unsigned short* WfP2,
        const float* prb1, const float* prb2,
        const unsigned short* eff, float* out)
{
    __shared__ __align__(16) unsigned char lds1[64 * 512];
    __shared__ __align__(16) unsigned char lds2[64 * 512];
    const int bir = blockIdx.x, tid = threadIdx.x;
    const int b = bir >> 10, r = bir & 15;
    const int ebase = (bir >> 4) * 1024 + r;

    {   // phase 0: lds1 = eff rows (step-0 output), lds2 = recomputed e0 rows
        int rlo = tid >> 5;
        int c0 = (tid & 31) * 8;
        for (int p = 0; p < 8; ++p) {
            int row = p * 8 + rlo;
            int swz = (c0 * 2) ^ ((row & 7) << 4);
            short8 sv = *(const short8*)(eff + (size_t)(ebase + row * 16) * 256 + c0);
            *(short8*)&lds1[row * 512 + swz] = sv;
            union { short8 s; unsigned short u[8]; } v;
            int nrj = b * 1024 + row * 16 + r;
#pragma unroll
            for (int e = 0; e < 8; ++e) {
                float x = X1[(size_t)bir * 256 + c0 + e] + X2[(size_t)nrj * 256 + c0 + e] + eeb[c0 + e];
                v.u[e] = f2bf(fmaxf(x, 0.f));
            }
            *(short8*)&lds2[row * 512 + swz] = v.s;
        }
    }
    __syncthreads();

    const int l = tid & 63, wv = tid >> 6, g = l >> 4, l15 = l & 15;
    f32x4 acc[4][4];
    // h = relu(eff @ ep1W1c + E1 + E2 + b1) -> lds1
    zero_acc(acc);
    gemm_tile<8, 512>(lds1, WfA, acc, wv, l);
    __syncthreads();
#pragma unroll
    for (int ni = 0; ni < 4; ++ni) {
        int col = 64 * wv + 16 * ni + l15;
        float e1b = E1[(size_t)bir * 256 + col] + b1[col];
#pragma unroll
        for (int mi = 0; mi < 4; ++mi)
#pragma unroll
            for (int q = 0; q < 4; ++q) {
                int row = 16 * mi + 4 * g + q;
                float e2 = E2[(size_t)(b * 1024 + row * 16 + r) * 256 + col];
                float h = fmaxf(acc[mi][ni][q] + e1b + e2, 0.f);
                *(unsigned short*)&lds1[row * 512 + ((col * 2) ^ ((row & 7) << 4))] = f2bf(h);
                acc[mi][ni][q] = 0.f;
            }
    }
    __syncthreads();
    // eff2 = relu(h @ ep1W2 + b2) -> lds1 (bf16, stays on-chip)
    gemm_tile<8, 512>(lds1, WfB, acc, wv, l);
    __syncthreads();
#pragma unroll
    for (int ni = 0; ni < 4; ++ni) {
        int col = 64 * wv + 16 * ni + l15;
        float bb = b2[col];
#pragma unroll
        for (int mi = 0; mi < 4; ++mi)
#pragma unroll
            for (int q = 0; q < 4; ++q) {
                int row = 16 * mi + 4 * g + q;
                *(unsigned short*)&lds1[row * 512 + ((col * 2) ^ ((row & 7) << 4))] =
                    f2bf(fmaxf(acc[mi][ni][q] + bb, 0.f));
            }
    }
    __syncthreads();
    // p = relu(eff2 @ prW1a + e0 @ prW1b + prb1) -> lds1
    zero_acc(acc);
    gemm_tile<8, 512>(lds1, WfPA, acc, wv, l);
    gemm_tile<8, 512>(lds2, WfPB, acc, wv, l);
    __syncthreads();
#pragma unroll
    for (int ni = 0; ni < 4; ++ni) {
        int col = 64 * wv + 16 * ni + l15;
        float pb = prb1[col];
#pragma unroll
        for (int mi = 0; mi < 4; ++mi)
#pragma unroll
            for (int q = 0; q < 4; ++q) {
                int row = 16 * mi + 4 * g + q;
                float p = fmaxf(acc[mi][ni][q] + pb, 0.f);
                *(unsigned short*)&lds1[row * 512 + ((col * 2) ^ ((row & 7) << 4))] = f2bf(p);
            }
    }
    __syncthreads();
    // out = p @ prW2 + prb2 : 64 cols, wave wv owns cols 16*wv..+15
    f32x4 acc3[4];
#pragma unroll
    for (int mi = 0; mi < 4; ++mi) acc3[mi] = (f32x4){0.f, 0.f, 0.f, 0.f};
    for (int kt = 0; kt < 8; ++kt) {
        short8 bf = *(const short8*)(WfP2 + (size_t)((kt * 4 + wv) * 64 + l) * 8);
#pragma unroll
        for (int mi = 0; mi < 4; ++mi) {
            short8 af = load_afrag<512>(lds1, 16 * mi + l15, kt, g);
            acc3[mi] = __builtin_amdgcn_mfma_f32_16x16x32_bf16(af, bf, acc3[mi], 0, 0, 0);
        }
    }
    int colo = 16 * wv + l15;
    float pb2 = prb2[colo];
#pragma unroll
    for (int mi = 0; mi < 4; ++mi)
#pragma unroll
        for (int q = 0; q < 4; ++q) {
            int row = 16 * mi + 4 * g + q;
            out[(size_t)(ebase + row * 16) * 64 + colo] = acc3[mi][q] + pb2;
        }
}

// ---------------- host ----------------
extern "C" void kernel_launch(void* const* d_in, const int* in_sizes, int n_in,
                              void* d_out, int out_size, void* d_ws, size_t ws_size,
                              hipStream_t stream)
{
    (void)in_sizes; (void)n_in; (void)out_size; (void)ws_size;
    const float* node_rep = (const float*)d_in[0];
    const float* neW   = (const float*)d_in[1];
    const float* neb   = (const float*)d_in[2];
    const float* eeW   = (const float*)d_in[3];
    const float* eeb   = (const float*)d_in[4];
    const float* npW1  = (const float*)d_in[5];
    const float* npb1  = (const float*)d_in[6];
    const float* npW2  = (const float*)d_in[7];
    const float* npb2  = (const float*)d_in[8];
    const float* ep0W1 = (const float*)d_in[9];
    const float* ep0b1 = (const float*)d_in[10];
    const float* ep0W2 = (const float*)d_in[11];
    const float* ep0b2 = (const float*)d_in[12];
    const float* ep1W1 = (const float*)d_in[13];
    const float* ep1b1 = (const float*)d_in[14];
    const float* ep1W2 = (const float*)d_in[15];
    const float* ep1b2 = (const float*)d_in[16];
    const float* prW1  = (const float*)d_in[17];
    const float* prb1  = (const float*)d_in[18];
    const float* prW2  = (const float*)d_in[19];
    const float* prb2  = (const float*)d_in[20];

    char* ws = (char*)d_ws;
    unsigned short* wsu = (unsigned short*)ws;
    auto wfull = [&](int i) { return (const unsigned short*)(ws + (size_t)i * WF_SZ); };
    unsigned short* node_enc = (unsigned short*)(ws + OFF_NENC);
    float* X1  = (float*)(ws + OFF_X1);
    float* X2  = (float*)(ws + OFF_X2);
    float* E1  = (float*)(ws + OFF_E1);
    float* E2  = (float*)(ws + OFF_E2);
    float* NE1 = (float*)(ws + OFF_NE1);
    float* agg = (float*)(ws + OFF_AGG);
    unsigned short* eff = (unsigned short*)(ws + OFF_EFF);
    const unsigned short* neWf  = (const unsigned short*)(ws + OFF_NEW);
    const unsigned short* eeW1f = (const unsigned short*)(ws + OFF_EE1);
    const unsigned short* eeW2f = (const unsigned short*)(ws + OFF_EE2);
    const unsigned short* prW2f = (const unsigned short*)(ws + OFF_PW2);

    kconv<<<dim3(1920), dim3(64), 0, stream>>>(ep0W1, ep0W2, ep1W1, ep1W2, prW1, prW2,
                                               npW1, npW2, neW, eeW, wsu);
    knode12<<<dim3(32), dim3(256), 0, stream>>>(node_rep, neb, neWf, eeW1f, eeW2f,
                                                wfull(6), wfull(7), wfull(10),
                                                node_enc, X1, X2, E1, E2, NE1);
    kstep1<<<dim3(2048), dim3(256), 0, stream>>>(X1, X2, eeb, E1, E2, ep0b1, ep0b2,
                                                 wfull(0), wfull(1), eff, agg);
    knode3<<<dim3(32), dim3(256), 0, stream>>>(node_enc, agg, NE1, npb1, npb2,
                                               wfull(8), wfull(9), wfull(11),
                                               wfull(12), wfull(13), E1, E2);
    kstep2pred<<<dim3(2048), dim3(256), 0, stream>>>(X1, X2, eeb, E1, E2, ep1b1, ep1b2,
                                                     wfull(2), wfull(3), wfull(4), wfull(5),
                                                     prW2f, prb1, prb2, eff, (float*)d_out);
}